// Round 6
// baseline (722.795 us; speedup 1.0000x reference)
//
#include <hip/hip_runtime.h>

// Problem constants
#define HD    16
#define DH    128
#define BB    2
#define SS    2048
#define DM    2048
#define NQKV  6144   // 3*HD*DH
#define MTOT  4096   // BB*SS

typedef short   bfx8  __attribute__((ext_vector_type(8)));   // 8 bf16 (4 VGPRs)
typedef float   f32x4 __attribute__((ext_vector_type(4)));

__device__ __forceinline__ unsigned short f2bf(float f) {
  union { float f; unsigned int u; } c; c.f = f;
  unsigned int u = c.u + 0x7FFFu + ((c.u >> 16) & 1u);
  return (unsigned short)(u >> 16);
}

__device__ __forceinline__ void gload_lds16(const unsigned short* g, unsigned short* l) {
  __builtin_amdgcn_global_load_lds(
      (const __attribute__((address_space(1))) unsigned int*)g,
      (__attribute__((address_space(3))) unsigned int*)l, 16, 0, 0);
}

// ---------------- f32 -> bf16 cast ----------------
__global__ __launch_bounds__(256) void f32_to_bf16_k(const float* __restrict__ in,
                                                     unsigned short* __restrict__ out, int n4) {
  int i = (blockIdx.x * 256 + threadIdx.x);
  if (i >= n4) return;
  const float4 v = *(const float4*)(in + (size_t)i * 4);
  ushort4 o;
  o.x = f2bf(v.x); o.y = f2bf(v.y); o.z = f2bf(v.z); o.w = f2bf(v.w);
  *(ushort4*)(out + (size_t)i * 4) = o;
}

// ---------------- f32 [R][C] -> bf16 [C][R] transpose ----------------
__global__ __launch_bounds__(256) void transpose_f32_bf16_k(const float* __restrict__ in,
                                                            unsigned short* __restrict__ out,
                                                            int R, int C) {
  __shared__ float t[32][33];
  const int c0 = blockIdx.x * 32, r0 = blockIdx.y * 32;
  const int tx = threadIdx.x & 31, ty = threadIdx.x >> 5;  // 32 x 8
#pragma unroll
  for (int i = 0; i < 4; i++) {
    int r = r0 + ty + i * 8;
    t[ty + i * 8][tx] = in[(size_t)r * C + c0 + tx];
  }
  __syncthreads();
#pragma unroll
  for (int i = 0; i < 4; i++) {
    int c = c0 + ty + i * 8;
    out[(size_t)c * R + r0 + tx] = f2bf(t[tx][ty + i * 8]);
  }
}

// ---------------- bf16 GEMM: C[M][ldc] = A[M][K] * Bt[N][K]^T ----------------
// 128x128 tile, BK=32, 4 waves (2x2 of 64x64), 16x16x32 MFMA, global_load_lds staging.
template <int OUT_BF16>
__global__ __launch_bounds__(256) void gemm_bt_k(const unsigned short* __restrict__ A,
                                                 const unsigned short* __restrict__ Bt,
                                                 void* __restrict__ Cp, int K, int ldc) {
  __shared__ __align__(16) unsigned short As[128 * 32];
  __shared__ __align__(16) unsigned short Bs[128 * 32];
  const int tid = threadIdx.x;
  const int lane = tid & 63, wid = tid >> 6;
  const int wr = wid >> 1, wc = wid & 1;
  const int cbase = lane & 15, rgrp = lane >> 4;
  const size_t m0 = (size_t)blockIdx.y * 128, n0 = (size_t)blockIdx.x * 128;

  f32x4 acc[4][4];
  const f32x4 z = {0.f, 0.f, 0.f, 0.f};
#pragma unroll
  for (int mf = 0; mf < 4; mf++)
#pragma unroll
    for (int nf = 0; nf < 4; nf++) acc[mf][nf] = z;

  const int nkt = K >> 5;
  for (int kt = 0; kt < nkt; ++kt) {
#pragma unroll
    for (int i = 0; i < 2; i++) {
      int idx = i * 256 + tid;
      int row = idx >> 2, cb = idx & 3;
      gload_lds16(A + (m0 + row) * K + (kt * 32 + cb * 8), As + idx * 8);
      gload_lds16(Bt + (n0 + row) * K + (kt * 32 + cb * 8), Bs + idx * 8);
    }
    __syncthreads();
    bfx8 af[4], bfr[4];
#pragma unroll
    for (int mf = 0; mf < 4; mf++)
      af[mf] = *(const bfx8*)(As + (wr * 64 + mf * 16 + cbase) * 32 + rgrp * 8);
#pragma unroll
    for (int nf = 0; nf < 4; nf++)
      bfr[nf] = *(const bfx8*)(Bs + (wc * 64 + nf * 16 + cbase) * 32 + rgrp * 8);
#pragma unroll
    for (int mf = 0; mf < 4; mf++)
#pragma unroll
      for (int nf = 0; nf < 4; nf++)
        acc[mf][nf] = __builtin_amdgcn_mfma_f32_16x16x32_bf16(af[mf], bfr[nf], acc[mf][nf], 0, 0, 0);
    __syncthreads();
  }

#pragma unroll
  for (int mf = 0; mf < 4; mf++)
#pragma unroll
    for (int nf = 0; nf < 4; nf++)
#pragma unroll
      for (int r = 0; r < 4; r++) {
        size_t row = m0 + wr * 64 + mf * 16 + rgrp * 4 + r;
        size_t col = n0 + wc * 64 + nf * 16 + cbase;
        if (OUT_BF16)
          ((unsigned short*)Cp)[row * ldc + col] = f2bf(acc[mf][nf][r]);
        else
          ((float*)Cp)[row * ldc + col] = acc[mf][nf][r];
      }
}

// ---------------- flash attention (bf16) ----------------
// Block: 256 threads = 4 waves, 64 q-rows per block (16 per wave), KVBLK=32.
// QKV layout: [b, s, h*384 + {q:0,k:128,v:256} + d]
__global__ __launch_bounds__(256) void attn_fwd_k(const unsigned short* __restrict__ qkv,
                                                  unsigned short* __restrict__ ao) {
  __shared__ __align__(16) unsigned short Klds[32 * 128];
  __shared__ __align__(16) unsigned short Vt[128 * 32];
  __shared__ __align__(16) unsigned short Plds[4][16 * 32];
  const int tid = threadIdx.x;
  const int lane = tid & 63, wid = tid >> 6;
  const int cbase = lane & 15, rgrp = lane >> 4;
  const int qt = blockIdx.x;
  const int b = (int)blockIdx.y >> 4, h = (int)blockIdx.y & 15;
  const int qbase = qt * 64;
  const size_t base = (size_t)b * SS * NQKV;

  // Q fragments (held in registers for the whole kernel)
  bfx8 qf[4];
  {
    const int qrow = qbase + wid * 16 + cbase;
    const unsigned short* qp = qkv + base + (size_t)qrow * NQKV + h * 384;
#pragma unroll
    for (int ks = 0; ks < 4; ks++) qf[ks] = *(const bfx8*)(qp + ks * 32 + rgrp * 8);
  }

  float m_run[4], l_run[4];
  f32x4 o[8];
  const f32x4 z = {0.f, 0.f, 0.f, 0.f};
#pragma unroll
  for (int r = 0; r < 4; r++) { m_run[r] = -1e30f; l_run[r] = 0.f; }
#pragma unroll
  for (int mb = 0; mb < 8; mb++) o[mb] = z;

  const float scale = 0.08838834764831845f;  // 1/sqrt(128)
  const int ntiles = (qbase + 64) >> 5;
  for (int t = 0; t < ntiles; ++t) {
    const int kvb = t * 32;
    // stage K [32][128] linear via global_load_lds
#pragma unroll
    for (int i = 0; i < 2; i++) {
      int idx = i * 256 + tid;
      int row = idx >> 4, seg = idx & 15;
      gload_lds16(qkv + base + (size_t)(kvb + row) * NQKV + h * 384 + 128 + seg * 8,
                  Klds + idx * 8);
    }
    // stage V transposed: Vt[d][kv]
#pragma unroll
    for (int i = 0; i < 2; i++) {
      int r = i * 16 + (tid >> 4), seg = tid & 15;
      const uint4 v4 = *(const uint4*)(qkv + base + (size_t)(kvb + r) * NQKV + h * 384 + 256 + seg * 8);
      const int d0 = seg * 8;
      Vt[(d0 + 0) * 32 + r] = (unsigned short)(v4.x);
      Vt[(d0 + 1) * 32 + r] = (unsigned short)(v4.x >> 16);
      Vt[(d0 + 2) * 32 + r] = (unsigned short)(v4.y);
      Vt[(d0 + 3) * 32 + r] = (unsigned short)(v4.y >> 16);
      Vt[(d0 + 4) * 32 + r] = (unsigned short)(v4.z);
      Vt[(d0 + 5) * 32 + r] = (unsigned short)(v4.z >> 16);
      Vt[(d0 + 6) * 32 + r] = (unsigned short)(v4.w);
      Vt[(d0 + 7) * 32 + r] = (unsigned short)(v4.w >> 16);
    }
    __syncthreads();

    // S = Q K^T  (two 16x16 col-tiles of kv)
    f32x4 s[2];
    s[0] = z; s[1] = z;
#pragma unroll
    for (int nf = 0; nf < 2; nf++)
#pragma unroll
      for (int ks = 0; ks < 4; ks++) {
        bfx8 kf = *(const bfx8*)(Klds + (nf * 16 + cbase) * 128 + ks * 32 + rgrp * 8);
        s[nf] = __builtin_amdgcn_mfma_f32_16x16x32_bf16(qf[ks], kf, s[nf], 0, 0, 0);
      }

    // scale + causal mask + online softmax (per q-row r; row-reduce over 16 lanes)
    float p[2][4], alpha[4];
#pragma unroll
    for (int r = 0; r < 4; r++) {
      const int qi = qbase + wid * 16 + rgrp * 4 + r;
      float s0 = s[0][r] * scale, s1 = s[1][r] * scale;
      if (kvb + cbase > qi) s0 = -1e30f;
      if (kvb + 16 + cbase > qi) s1 = -1e30f;
      float tm = fmaxf(s0, s1);
#pragma unroll
      for (int off = 1; off < 16; off <<= 1) tm = fmaxf(tm, __shfl_xor(tm, off));
      const float mnew = fmaxf(m_run[r], tm);
      const float p0 = __expf(s0 - mnew), p1 = __expf(s1 - mnew);
      float rs = p0 + p1;
#pragma unroll
      for (int off = 1; off < 16; off <<= 1) rs += __shfl_xor(rs, off);
      alpha[r] = __expf(m_run[r] - mnew);
      l_run[r] = l_run[r] * alpha[r] + rs;
      m_run[r] = mnew;
      p[0][r] = p0; p[1][r] = p1;
    }
#pragma unroll
    for (int mb = 0; mb < 8; mb++)
#pragma unroll
      for (int r = 0; r < 4; r++) o[mb][r] *= alpha[r];

    // P (C-layout) -> LDS -> A-fragment layout
#pragma unroll
    for (int nf = 0; nf < 2; nf++)
#pragma unroll
      for (int r = 0; r < 4; r++)
        Plds[wid][(rgrp * 4 + r) * 32 + nf * 16 + cbase] = f2bf(p[nf][r]);
    const bfx8 pf = *(const bfx8*)(&Plds[wid][cbase * 32 + rgrp * 8]);

    // O += P * V
#pragma unroll
    for (int mb = 0; mb < 8; mb++) {
      bfx8 vf = *(const bfx8*)(Vt + (mb * 16 + cbase) * 32 + rgrp * 8);
      o[mb] = __builtin_amdgcn_mfma_f32_16x16x32_bf16(pf, vf, o[mb], 0, 0, 0);
    }
    __syncthreads();
  }

  // normalize + write AO [b*S + q][h*128 + d] (bf16)
#pragma unroll
  for (int r = 0; r < 4; r++) l_run[r] = 1.0f / l_run[r];
  const int qrow0 = qbase + wid * 16 + rgrp * 4;
#pragma unroll
  for (int mb = 0; mb < 8; mb++)
#pragma unroll
    for (int r = 0; r < 4; r++) {
      size_t idx = ((size_t)(b * SS + qrow0 + r)) * (size_t)DM + h * DH + mb * 16 + cbase;
      ao[idx] = f2bf(o[mb][r] * l_run[r]);
    }
}

extern "C" void kernel_launch(void* const* d_in, const int* in_sizes, int n_in,
                              void* d_out, int out_size, void* d_ws, size_t ws_size,
                              hipStream_t stream) {
  (void)in_sizes; (void)n_in; (void)out_size; (void)ws_size;
  const float* x     = (const float*)d_in[0];
  const float* w_in  = (const float*)d_in[1];
  const float* w_out = (const float*)d_in[2];
  float* out = (float*)d_out;

  char* ws = (char*)d_ws;
  unsigned short* Xb  = (unsigned short*)(ws);                       // 4096x2048 bf16 (16 MB)
  unsigned short* Wit = (unsigned short*)(ws + 16777216ull);         // 6144x2048 bf16 (24 MB)
  unsigned short* Wot = (unsigned short*)(ws + 41943040ull);         // 2048x2048 bf16 (8 MB)
  unsigned short* QKV = (unsigned short*)(ws + 50331648ull);         // 4096x6144 bf16 (48 MB)
  unsigned short* AO  = (unsigned short*)(ws + 100663296ull);        // 4096x2048 bf16 (16 MB)

  // x -> bf16
  f32_to_bf16_k<<<MTOT * DM / 4 / 256, 256, 0, stream>>>(x, Xb, MTOT * DM / 4);
  // w_in [2048][6144] -> Wit [6144][2048] bf16
  transpose_f32_bf16_k<<<dim3(NQKV / 32, DM / 32), 256, 0, stream>>>(w_in, Wit, DM, NQKV);
  // w_out [2048][2048] -> Wot [2048][2048]^T bf16
  transpose_f32_bf16_k<<<dim3(DM / 32, DM / 32), 256, 0, stream>>>(w_out, Wot, DM, DM);
  // QKV = Xb @ Wit^T  [4096][6144] bf16
  gemm_bt_k<1><<<dim3(NQKV / 128, MTOT / 128), 256, 0, stream>>>(Xb, Wit, QKV, DM, NQKV);
  // attention -> AO [4096][2048] bf16
  attn_fwd_k<<<dim3(SS / 64, BB * HD), 256, 0, stream>>>(QKV, AO);
  // out = AO @ Wot^T  [4096][2048] f32
  gemm_bt_k<0><<<dim3(DM / 128, MTOT / 128), 256, 0, stream>>>(AO, Wot, out, DM, DM);
}

// Round 7
// 379.717 us; speedup vs baseline: 1.9035x; 1.9035x over previous
//
#include <hip/hip_runtime.h>

// Problem constants
#define HD    16
#define DH    128
#define BB    2
#define SS    2048
#define DM    2048
#define NQKV  6144   // 3*HD*DH
#define MTOT  4096   // BB*SS

typedef short   bfx8  __attribute__((ext_vector_type(8)));   // 8 bf16 (4 VGPRs)
typedef float   f32x4 __attribute__((ext_vector_type(4)));

__device__ __forceinline__ unsigned short f2bf(float f) {
  union { float f; unsigned int u; } c; c.f = f;
  unsigned int u = c.u + 0x7FFFu + ((c.u >> 16) & 1u);
  return (unsigned short)(u >> 16);
}

__device__ __forceinline__ void gload_lds16(const unsigned short* g, unsigned short* l) {
  __builtin_amdgcn_global_load_lds(
      (const __attribute__((address_space(1))) unsigned int*)g,
      (__attribute__((address_space(3))) unsigned int*)l, 16, 0, 0);
}

// ---------------- f32 -> bf16 cast ----------------
__global__ __launch_bounds__(256) void f32_to_bf16_k(const float* __restrict__ in,
                                                     unsigned short* __restrict__ out, int n4) {
  int i = (blockIdx.x * 256 + threadIdx.x);
  if (i >= n4) return;
  const float4 v = *(const float4*)(in + (size_t)i * 4);
  ushort4 o;
  o.x = f2bf(v.x); o.y = f2bf(v.y); o.z = f2bf(v.z); o.w = f2bf(v.w);
  *(ushort4*)(out + (size_t)i * 4) = o;
}

// ---------------- f32 [R][C] -> bf16 [C][R] transpose ----------------
__global__ __launch_bounds__(256) void transpose_f32_bf16_k(const float* __restrict__ in,
                                                            unsigned short* __restrict__ out,
                                                            int R, int C) {
  __shared__ float t[32][33];
  const int c0 = blockIdx.x * 32, r0 = blockIdx.y * 32;
  const int tx = threadIdx.x & 31, ty = threadIdx.x >> 5;  // 32 x 8
#pragma unroll
  for (int i = 0; i < 4; i++) {
    int r = r0 + ty + i * 8;
    t[ty + i * 8][tx] = in[(size_t)r * C + c0 + tx];
  }
  __syncthreads();
#pragma unroll
  for (int i = 0; i < 4; i++) {
    int c = c0 + ty + i * 8;
    out[(size_t)c * R + r0 + tx] = f2bf(t[tx][ty + i * 8]);
  }
}

// ---------------- bf16 GEMM: C = A[M][K] * Bt[N][K]^T ----------------
// 128x128 tile, BK=32, 4 waves (2x2 of 64x64), 16x16x32 MFMA, global_load_lds staging.
// QKV==0: C0 = f32 [M][ldc]. QKV==1: split epilogue -> Qg/Kg [b][h][s][d], Vg [b][h][d][s].
template <int QKV>
__global__ __launch_bounds__(256) void gemm_bt_k(const unsigned short* __restrict__ A,
                                                 const unsigned short* __restrict__ Bt,
                                                 void* __restrict__ C0, void* __restrict__ C1,
                                                 void* __restrict__ C2, int K, int ldc) {
  __shared__ __align__(16) unsigned short As[128 * 32];
  __shared__ __align__(16) unsigned short Bs[128 * 32];
  const int tid = threadIdx.x;
  const int lane = tid & 63, wid = tid >> 6;
  const int wr = wid >> 1, wc = wid & 1;
  const int cbase = lane & 15, rgrp = lane >> 4;
  const size_t m0 = (size_t)blockIdx.y * 128, n0 = (size_t)blockIdx.x * 128;

  f32x4 acc[4][4];
  const f32x4 z = {0.f, 0.f, 0.f, 0.f};
#pragma unroll
  for (int mf = 0; mf < 4; mf++)
#pragma unroll
    for (int nf = 0; nf < 4; nf++) acc[mf][nf] = z;

  const int nkt = K >> 5;
  for (int kt = 0; kt < nkt; ++kt) {
#pragma unroll
    for (int i = 0; i < 2; i++) {
      int idx = i * 256 + tid;
      int row = idx >> 2, cb = idx & 3;
      gload_lds16(A + (m0 + row) * K + (kt * 32 + cb * 8), As + idx * 8);
      gload_lds16(Bt + (n0 + row) * K + (kt * 32 + cb * 8), Bs + idx * 8);
    }
    __syncthreads();
    bfx8 af[4], bfr[4];
#pragma unroll
    for (int mf = 0; mf < 4; mf++)
      af[mf] = *(const bfx8*)(As + (wr * 64 + mf * 16 + cbase) * 32 + rgrp * 8);
#pragma unroll
    for (int nf = 0; nf < 4; nf++)
      bfr[nf] = *(const bfx8*)(Bs + (wc * 64 + nf * 16 + cbase) * 32 + rgrp * 8);
#pragma unroll
    for (int mf = 0; mf < 4; mf++)
#pragma unroll
      for (int nf = 0; nf < 4; nf++)
        acc[mf][nf] = __builtin_amdgcn_mfma_f32_16x16x32_bf16(af[mf], bfr[nf], acc[mf][nf], 0, 0, 0);
    __syncthreads();
  }

  if (QKV) {
    // n0 block maps to a single (h, t) class: kblk in [0,48), h = kblk/3, t = kblk%3
    const int kblk = (int)blockIdx.x;
    const int h = kblk / 3, t = kblk - 3 * (kblk / 3);
#pragma unroll
    for (int mf = 0; mf < 4; mf++)
#pragma unroll
      for (int nf = 0; nf < 4; nf++) {
        const int d = wc * 64 + nf * 16 + cbase;
        const int row0 = (int)m0 + wr * 64 + mf * 16 + rgrp * 4;
        const int bb = row0 >> 11;        // same batch for r=0..3
        const int s0 = row0 & 2047;
        if (t == 2) {
          ushort4 v;
          v.x = f2bf(acc[mf][nf][0]); v.y = f2bf(acc[mf][nf][1]);
          v.z = f2bf(acc[mf][nf][2]); v.w = f2bf(acc[mf][nf][3]);
          unsigned short* dstV = (unsigned short*)C2;
          *(ushort4*)(dstV + ((size_t)(bb * HD + h) * DH + d) * SS + s0) = v;
        } else {
          unsigned short* dst = (unsigned short*)(t == 0 ? C0 : C1);
#pragma unroll
          for (int r = 0; r < 4; r++)
            dst[((size_t)(bb * HD + h) * SS + s0 + r) * DH + d] = f2bf(acc[mf][nf][r]);
        }
      }
  } else {
    float* C = (float*)C0;
#pragma unroll
    for (int mf = 0; mf < 4; mf++)
#pragma unroll
      for (int nf = 0; nf < 4; nf++)
#pragma unroll
        for (int r = 0; r < 4; r++) {
          size_t row = m0 + wr * 64 + mf * 16 + rgrp * 4 + r;
          size_t col = n0 + wc * 64 + nf * 16 + cbase;
          C[row * ldc + col] = acc[mf][nf][r];
        }
  }
}

// ---------------- flash attention (bf16) ----------------
// 4 waves, 64 q-rows per q-tile (16 per wave), KVBLK=32.
// Balanced pairing: block pi handles q-tiles pi and 31-pi (66 kv-iters each).
// K staged linear [32][128]; V staged from pre-transposed Vg as [128][32]; both via DMA.
__global__ __launch_bounds__(256) void attn_fwd_k(const unsigned short* __restrict__ Qg,
                                                  const unsigned short* __restrict__ Kg,
                                                  const unsigned short* __restrict__ Vg,
                                                  unsigned short* __restrict__ ao) {
  __shared__ __align__(16) unsigned short Klds[32 * 128];
  __shared__ __align__(16) unsigned short Vt[128 * 32];
  __shared__ __align__(16) unsigned short Plds[4][16 * 40];  // stride 40: b128-aligned, spreads banks
  const int tid = threadIdx.x;
  const int lane = tid & 63, wid = tid >> 6;
  const int cbase = lane & 15, rgrp = lane >> 4;
  const int b = (int)blockIdx.y >> 4, h = (int)blockIdx.y & 15;
  const unsigned short* qp0 = Qg + (size_t)(b * HD + h) * SS * DH;
  const unsigned short* kp  = Kg + (size_t)(b * HD + h) * SS * DH;
  const unsigned short* vp  = Vg + (size_t)(b * HD + h) * DH * SS;
  const float scale = 0.08838834764831845f;  // 1/sqrt(128)
  const f32x4 z = {0.f, 0.f, 0.f, 0.f};

  for (int half = 0; half < 2; half++) {
    const int qt = half ? (31 - (int)blockIdx.x) : (int)blockIdx.x;
    const int qbase = qt * 64;

    bfx8 qf[4];
    {
      const unsigned short* qp = qp0 + (size_t)(qbase + wid * 16 + cbase) * DH;
#pragma unroll
      for (int ks = 0; ks < 4; ks++) qf[ks] = *(const bfx8*)(qp + ks * 32 + rgrp * 8);
    }

    float m_run[4], l_run[4];
    f32x4 o[8];
#pragma unroll
    for (int r = 0; r < 4; r++) { m_run[r] = -1e30f; l_run[r] = 0.f; }
#pragma unroll
    for (int mb = 0; mb < 8; mb++) o[mb] = z;

    const int ntiles = (qbase >> 5) + 2;
    for (int t = 0; t < ntiles; ++t) {
      const int kvb = t * 32;
      // stage K [32][128] linear (contiguous 8 KB)
#pragma unroll
      for (int i = 0; i < 2; i++) {
        int idx = i * 256 + tid;
        gload_lds16(kp + (size_t)kvb * DH + idx * 8, Klds + idx * 8);
      }
      // stage V^T tile [128 d][32 kv] from Vg[d][s]
#pragma unroll
      for (int i = 0; i < 2; i++) {
        int idx = i * 256 + tid;
        int d = idx >> 2, seg = idx & 3;
        gload_lds16(vp + (size_t)d * SS + kvb + seg * 8, Vt + idx * 8);
      }
      __syncthreads();

      // S = Q K^T  (two 16x16 kv-col tiles)
      f32x4 s[2];
      s[0] = z; s[1] = z;
#pragma unroll
      for (int nf = 0; nf < 2; nf++)
#pragma unroll
        for (int ks = 0; ks < 4; ks++) {
          bfx8 kf = *(const bfx8*)(Klds + (nf * 16 + cbase) * 128 + ks * 32 + rgrp * 8);
          s[nf] = __builtin_amdgcn_mfma_f32_16x16x32_bf16(qf[ks], kf, s[nf], 0, 0, 0);
        }

      // scale + causal mask + online softmax (row-reduce over 16 lanes)
      float p[2][4], alpha[4];
#pragma unroll
      for (int r = 0; r < 4; r++) {
        const int qi = qbase + wid * 16 + rgrp * 4 + r;
        float s0 = s[0][r] * scale, s1 = s[1][r] * scale;
        if (kvb + cbase > qi) s0 = -1e30f;
        if (kvb + 16 + cbase > qi) s1 = -1e30f;
        float tm = fmaxf(s0, s1);
#pragma unroll
        for (int off = 1; off < 16; off <<= 1) tm = fmaxf(tm, __shfl_xor(tm, off));
        const float mnew = fmaxf(m_run[r], tm);
        const float p0 = __expf(s0 - mnew), p1 = __expf(s1 - mnew);
        float rs = p0 + p1;
#pragma unroll
        for (int off = 1; off < 16; off <<= 1) rs += __shfl_xor(rs, off);
        alpha[r] = __expf(m_run[r] - mnew);
        l_run[r] = l_run[r] * alpha[r] + rs;
        m_run[r] = mnew;
        p[0][r] = p0; p[1][r] = p1;
      }
#pragma unroll
      for (int mb = 0; mb < 8; mb++)
#pragma unroll
        for (int r = 0; r < 4; r++) o[mb][r] *= alpha[r];

      // P (C-layout) -> LDS (stride 40) -> A-fragment layout
#pragma unroll
      for (int nf = 0; nf < 2; nf++)
#pragma unroll
        for (int r = 0; r < 4; r++)
          Plds[wid][(rgrp * 4 + r) * 40 + nf * 16 + cbase] = f2bf(p[nf][r]);
      const bfx8 pf = *(const bfx8*)(&Plds[wid][cbase * 40 + rgrp * 8]);

      // O += P * V
#pragma unroll
      for (int mb = 0; mb < 8; mb++) {
        bfx8 vf = *(const bfx8*)(Vt + (mb * 16 + cbase) * 32 + rgrp * 8);
        o[mb] = __builtin_amdgcn_mfma_f32_16x16x32_bf16(pf, vf, o[mb], 0, 0, 0);
      }
      __syncthreads();
    }

    // normalize + write AO [b*S + q][h*128 + d] (bf16)
    float rinv[4];
#pragma unroll
    for (int r = 0; r < 4; r++) rinv[r] = 1.0f / l_run[r];
    const int qrow0 = qbase + wid * 16 + rgrp * 4;
#pragma unroll
    for (int mb = 0; mb < 8; mb++)
#pragma unroll
      for (int r = 0; r < 4; r++) {
        size_t idx = ((size_t)(b * SS + qrow0 + r)) * (size_t)DM + h * DH + mb * 16 + cbase;
        ao[idx] = f2bf(o[mb][r] * rinv[r]);
      }
  }
}

extern "C" void kernel_launch(void* const* d_in, const int* in_sizes, int n_in,
                              void* d_out, int out_size, void* d_ws, size_t ws_size,
                              hipStream_t stream) {
  (void)in_sizes; (void)n_in; (void)out_size; (void)ws_size;
  const float* x     = (const float*)d_in[0];
  const float* w_in  = (const float*)d_in[1];
  const float* w_out = (const float*)d_in[2];
  float* out = (float*)d_out;

  char* ws = (char*)d_ws;
  unsigned short* Xb  = (unsigned short*)(ws);                     // 16 MB  [4096][2048]
  unsigned short* Wit = (unsigned short*)(ws + (16ull << 20));     // 24 MB  [6144][2048]
  unsigned short* Wot = (unsigned short*)(ws + (40ull << 20));     //  8 MB  [2048][2048]
  unsigned short* Qg  = (unsigned short*)(ws + (48ull << 20));     // 16 MB  [b][h][s][d]
  unsigned short* Kg  = (unsigned short*)(ws + (64ull << 20));     // 16 MB  [b][h][s][d]
  unsigned short* Vg  = (unsigned short*)(ws + (80ull << 20));     // 16 MB  [b][h][d][s]
  unsigned short* AO  = (unsigned short*)(ws + (96ull << 20));     // 16 MB  [4096][2048]

  // x -> bf16
  f32_to_bf16_k<<<MTOT * DM / 4 / 256, 256, 0, stream>>>(x, Xb, MTOT * DM / 4);
  // w_in [2048][6144] -> Wit [6144][2048] bf16
  transpose_f32_bf16_k<<<dim3(NQKV / 32, DM / 32), 256, 0, stream>>>(w_in, Wit, DM, NQKV);
  // w_out [2048][2048] -> Wot transposed bf16
  transpose_f32_bf16_k<<<dim3(DM / 32, DM / 32), 256, 0, stream>>>(w_out, Wot, DM, DM);
  // QKV projection with split epilogue -> Qg, Kg, Vg(transposed)
  gemm_bt_k<1><<<dim3(NQKV / 128, MTOT / 128), 256, 0, stream>>>(Xb, Wit, Qg, Kg, Vg, DM, 0);
  // attention -> AO
  attn_fwd_k<<<dim3(16, BB * HD), 256, 0, stream>>>(Qg, Kg, Vg, AO);
  // out = AO @ Wot^T (f32)
  gemm_bt_k<0><<<dim3(DM / 128, MTOT / 128), 256, 0, stream>>>(AO, Wot, out, nullptr, nullptr, DM, DM);
}

// Round 8
// 354.996 us; speedup vs baseline: 2.0361x; 1.0696x over previous
//
#include <hip/hip_runtime.h>

// Problem constants
#define HD    16
#define DH    128
#define BB    2
#define SS    2048
#define DM    2048
#define NQKV  6144   // 3*HD*DH
#define MTOT  4096   // BB*SS

typedef short   bfx8  __attribute__((ext_vector_type(8)));   // 8 bf16 (4 VGPRs)
typedef float   f32x4 __attribute__((ext_vector_type(4)));

__device__ __forceinline__ unsigned short f2bf(float f) {
  union { float f; unsigned int u; } c; c.f = f;
  unsigned int u = c.u + 0x7FFFu + ((c.u >> 16) & 1u);
  return (unsigned short)(u >> 16);
}

__device__ __forceinline__ void gload_lds16(const unsigned short* g, unsigned short* l) {
  __builtin_amdgcn_global_load_lds(
      (const __attribute__((address_space(1))) unsigned int*)g,
      (__attribute__((address_space(3))) unsigned int*)l, 16, 0, 0);
}

// ---------------- f32 -> bf16 cast ----------------
__global__ __launch_bounds__(256) void f32_to_bf16_k(const float* __restrict__ in,
                                                     unsigned short* __restrict__ out, int n4) {
  int i = (blockIdx.x * 256 + threadIdx.x);
  if (i >= n4) return;
  const float4 v = *(const float4*)(in + (size_t)i * 4);
  ushort4 o;
  o.x = f2bf(v.x); o.y = f2bf(v.y); o.z = f2bf(v.z); o.w = f2bf(v.w);
  *(ushort4*)(out + (size_t)i * 4) = o;
}

// ---------------- f32 [R][C] -> bf16 [C][R] transpose ----------------
__global__ __launch_bounds__(256) void transpose_f32_bf16_k(const float* __restrict__ in,
                                                            unsigned short* __restrict__ out,
                                                            int R, int C) {
  __shared__ float t[32][33];
  const int c0 = blockIdx.x * 32, r0 = blockIdx.y * 32;
  const int tx = threadIdx.x & 31, ty = threadIdx.x >> 5;  // 32 x 8
#pragma unroll
  for (int i = 0; i < 4; i++) {
    int r = r0 + ty + i * 8;
    t[ty + i * 8][tx] = in[(size_t)r * C + c0 + tx];
  }
  __syncthreads();
#pragma unroll
  for (int i = 0; i < 4; i++) {
    int c = c0 + ty + i * 8;
    out[(size_t)c * R + r0 + tx] = f2bf(t[tx][ty + i * 8]);
  }
}

// ---------------- bf16 GEMM: C = A[M][K] * Bt[N][K]^T ----------------
// 128x128 tile, BK=32, 4 waves (2x2 of 64x64), 16x16x32 MFMA, global_load_lds staging.
// QKV==0: C0 = f32 [M][ldc]. QKV==1: split epilogue -> Qg/Kg [b][h][s][d], Vg [b][h][d][s].
template <int QKV>
__global__ __launch_bounds__(256) void gemm_bt_k(const unsigned short* __restrict__ A,
                                                 const unsigned short* __restrict__ Bt,
                                                 void* __restrict__ C0, void* __restrict__ C1,
                                                 void* __restrict__ C2, int K, int ldc) {
  __shared__ __align__(16) unsigned short As[128 * 32];
  __shared__ __align__(16) unsigned short Bs[128 * 32];
  const int tid = threadIdx.x;
  const int lane = tid & 63, wid = tid >> 6;
  const int wr = wid >> 1, wc = wid & 1;
  const int cbase = lane & 15, rgrp = lane >> 4;
  const size_t m0 = (size_t)blockIdx.y * 128, n0 = (size_t)blockIdx.x * 128;

  f32x4 acc[4][4];
  const f32x4 z = {0.f, 0.f, 0.f, 0.f};
#pragma unroll
  for (int mf = 0; mf < 4; mf++)
#pragma unroll
    for (int nf = 0; nf < 4; nf++) acc[mf][nf] = z;

  const int nkt = K >> 5;
  for (int kt = 0; kt < nkt; ++kt) {
#pragma unroll
    for (int i = 0; i < 2; i++) {
      int idx = i * 256 + tid;
      int row = idx >> 2, cb = idx & 3;
      gload_lds16(A + (m0 + row) * K + (kt * 32 + cb * 8), As + idx * 8);
      gload_lds16(Bt + (n0 + row) * K + (kt * 32 + cb * 8), Bs + idx * 8);
    }
    __syncthreads();
    bfx8 af[4], bfr[4];
#pragma unroll
    for (int mf = 0; mf < 4; mf++)
      af[mf] = *(const bfx8*)(As + (wr * 64 + mf * 16 + cbase) * 32 + rgrp * 8);
#pragma unroll
    for (int nf = 0; nf < 4; nf++)
      bfr[nf] = *(const bfx8*)(Bs + (wc * 64 + nf * 16 + cbase) * 32 + rgrp * 8);
#pragma unroll
    for (int mf = 0; mf < 4; mf++)
#pragma unroll
      for (int nf = 0; nf < 4; nf++)
        acc[mf][nf] = __builtin_amdgcn_mfma_f32_16x16x32_bf16(af[mf], bfr[nf], acc[mf][nf], 0, 0, 0);
    __syncthreads();
  }

  if (QKV) {
    // n0 block maps to a single (h, t) class: kblk in [0,48), h = kblk/3, t = kblk%3
    const int kblk = (int)blockIdx.x;
    const int h = kblk / 3, t = kblk - 3 * (kblk / 3);
#pragma unroll
    for (int mf = 0; mf < 4; mf++)
#pragma unroll
      for (int nf = 0; nf < 4; nf++) {
        const int d = wc * 64 + nf * 16 + cbase;
        const int row0 = (int)m0 + wr * 64 + mf * 16 + rgrp * 4;
        const int bb = row0 >> 11;        // same batch for r=0..3
        const int s0 = row0 & 2047;
        if (t == 2) {
          ushort4 v;
          v.x = f2bf(acc[mf][nf][0]); v.y = f2bf(acc[mf][nf][1]);
          v.z = f2bf(acc[mf][nf][2]); v.w = f2bf(acc[mf][nf][3]);
          unsigned short* dstV = (unsigned short*)C2;
          *(ushort4*)(dstV + ((size_t)(bb * HD + h) * DH + d) * SS + s0) = v;
        } else {
          unsigned short* dst = (unsigned short*)(t == 0 ? C0 : C1);
#pragma unroll
          for (int r = 0; r < 4; r++)
            dst[((size_t)(bb * HD + h) * SS + s0 + r) * DH + d] = f2bf(acc[mf][nf][r]);
        }
      }
  } else {
    float* C = (float*)C0;
#pragma unroll
    for (int mf = 0; mf < 4; mf++)
#pragma unroll
      for (int nf = 0; nf < 4; nf++)
#pragma unroll
        for (int r = 0; r < 4; r++) {
          size_t row = m0 + wr * 64 + mf * 16 + rgrp * 4 + r;
          size_t col = n0 + wc * 64 + nf * 16 + cbase;
          C[row * ldc + col] = acc[mf][nf][r];
        }
  }
}

// ---------------- flash attention (bf16) ----------------
// 4 waves, 64 q-rows per block (16 per wave), KVBLK=64, XOR-swizzled LDS.
// Grid: 1024 blocks 1-D. bh=(bid%8)*4+(bid/8)%4 (4 bh per XCD -> K/V L2-resident),
// qt = 31 - bid/32 (heavy blocks dispatched first).
// K/V^T staged via global_load_lds with PRE-SWIZZLED global source (linear LDS dest);
// swizzle: byte_in_row ^= (row&7)<<4. All LDS reads apply the same XOR -> <=2-way conflicts.
__global__ __launch_bounds__(256) void attn_fwd_k(const unsigned short* __restrict__ Qg,
                                                  const unsigned short* __restrict__ Kg,
                                                  const unsigned short* __restrict__ Vg,
                                                  unsigned short* __restrict__ ao) {
  __shared__ __align__(16) unsigned short Klds[64 * 128];   // 16 KB, row=kv, 256 B/row
  __shared__ __align__(16) unsigned short Vt[128 * 64];     // 16 KB, row=d,  128 B/row
  __shared__ __align__(16) unsigned short Plds[4][16 * 64]; //  8 KB, per-wave, 128 B/row
  const int tid = threadIdx.x;
  const int lane = tid & 63, wid = tid >> 6;
  const int cbase = lane & 15, rgrp = lane >> 4;

  const int bid = (int)blockIdx.x;
  const int bh = (bid & 7) * 4 + ((bid >> 3) & 3);
  const int qt = 31 - (bid >> 5);
  const int b = bh >> 4, h = bh & 15;
  const int qbase = qt * 64;

  const unsigned short* qp0 = Qg + (size_t)(b * HD + h) * SS * DH;
  const unsigned short* kp  = Kg + (size_t)(b * HD + h) * SS * DH;
  const unsigned short* vp  = Vg + (size_t)(b * HD + h) * DH * SS;
  const float scale = 0.08838834764831845f;  // 1/sqrt(128)
  const f32x4 z = {0.f, 0.f, 0.f, 0.f};

  bfx8 qf[4];
  {
    const unsigned short* qp = qp0 + (size_t)(qbase + wid * 16 + cbase) * DH;
#pragma unroll
    for (int ks = 0; ks < 4; ks++) qf[ks] = *(const bfx8*)(qp + ks * 32 + rgrp * 8);
  }

  float m_run[4], l_run[4];
  f32x4 o[8];
#pragma unroll
  for (int r = 0; r < 4; r++) { m_run[r] = -1e30f; l_run[r] = 0.f; }
#pragma unroll
  for (int mb = 0; mb < 8; mb++) o[mb] = z;

  const int ntiles = qt + 1;
  for (int t = 0; t < ntiles; ++t) {
    const int kvb = t * 64;
    // stage K [64 kv][128 d]: linear dest, pre-swizzled source
#pragma unroll
    for (int i = 0; i < 4; i++) {
      int idx = i * 256 + tid;
      int r = idx >> 4, bofs = (idx & 15) * 16;
      gload_lds16(kp + (size_t)(kvb + r) * DH + ((bofs ^ ((r & 7) << 4)) >> 1),
                  Klds + idx * 8);
    }
    // stage V^T [128 d][64 kv]: linear dest, pre-swizzled source
#pragma unroll
    for (int i = 0; i < 4; i++) {
      int idx = i * 256 + tid;
      int d = idx >> 3, bofs = (idx & 7) * 16;
      gload_lds16(vp + (size_t)d * SS + kvb + ((bofs ^ ((d & 7) << 4)) >> 1),
                  Vt + idx * 8);
    }
    __syncthreads();

    // S = Q K^T  (four 16x16 kv-col tiles)
    f32x4 s[4];
#pragma unroll
    for (int nf = 0; nf < 4; nf++) s[nf] = z;
#pragma unroll
    for (int nf = 0; nf < 4; nf++) {
      const int row = nf * 16 + cbase;
#pragma unroll
      for (int ks = 0; ks < 4; ks++) {
        bfx8 kf = *(const bfx8*)(Klds + ((row * 256 + ((ks * 64 + rgrp * 16) ^ ((row & 7) << 4))) >> 1));
        s[nf] = __builtin_amdgcn_mfma_f32_16x16x32_bf16(qf[ks], kf, s[nf], 0, 0, 0);
      }
    }

    // scale + causal mask (diagonal tile only) + online softmax
    const bool diag = (t == ntiles - 1);
    float p[4][4], alpha[4];
#pragma unroll
    for (int r = 0; r < 4; r++) {
      const int qi = qbase + wid * 16 + rgrp * 4 + r;
      float sv[4];
#pragma unroll
      for (int nf = 0; nf < 4; nf++) sv[nf] = s[nf][r] * scale;
      if (diag) {
#pragma unroll
        for (int nf = 0; nf < 4; nf++)
          if (kvb + nf * 16 + cbase > qi) sv[nf] = -1e30f;
      }
      float tm = fmaxf(fmaxf(sv[0], sv[1]), fmaxf(sv[2], sv[3]));
#pragma unroll
      for (int off = 1; off < 16; off <<= 1) tm = fmaxf(tm, __shfl_xor(tm, off));
      const float mnew = fmaxf(m_run[r], tm);
      float rs = 0.f;
#pragma unroll
      for (int nf = 0; nf < 4; nf++) { p[nf][r] = __expf(sv[nf] - mnew); rs += p[nf][r]; }
#pragma unroll
      for (int off = 1; off < 16; off <<= 1) rs += __shfl_xor(rs, off);
      alpha[r] = __expf(m_run[r] - mnew);
      l_run[r] = l_run[r] * alpha[r] + rs;
      m_run[r] = mnew;
    }
#pragma unroll
    for (int mb = 0; mb < 8; mb++)
#pragma unroll
      for (int r = 0; r < 4; r++) o[mb][r] *= alpha[r];

    // P (C-layout) -> swizzled LDS -> A-fragment layout
#pragma unroll
    for (int nf = 0; nf < 4; nf++)
#pragma unroll
      for (int r = 0; r < 4; r++) {
        const int row = rgrp * 4 + r;
        Plds[wid][(row * 128 + ((nf * 32 + cbase * 2) ^ ((row & 7) << 4))) >> 1] = f2bf(p[nf][r]);
      }
    bfx8 pf[2];
#pragma unroll
    for (int k2 = 0; k2 < 2; k2++)
      pf[k2] = *(const bfx8*)(&Plds[wid][(cbase * 128 + ((k2 * 64 + rgrp * 16) ^ ((cbase & 7) << 4))) >> 1]);

    // O += P * V  (two k-slices of 32)
#pragma unroll
    for (int mb = 0; mb < 8; mb++) {
      const int d = mb * 16 + cbase;
#pragma unroll
      for (int k2 = 0; k2 < 2; k2++) {
        bfx8 vf = *(const bfx8*)(Vt + ((d * 128 + ((k2 * 64 + rgrp * 16) ^ ((d & 7) << 4))) >> 1));
        o[mb] = __builtin_amdgcn_mfma_f32_16x16x32_bf16(pf[k2], vf, o[mb], 0, 0, 0);
      }
    }
    __syncthreads();
  }

  // normalize + write AO [b*S + q][h*128 + d] (bf16)
  float rinv[4];
#pragma unroll
  for (int r = 0; r < 4; r++) rinv[r] = 1.0f / l_run[r];
  const int qrow0 = qbase + wid * 16 + rgrp * 4;
#pragma unroll
  for (int mb = 0; mb < 8; mb++)
#pragma unroll
    for (int r = 0; r < 4; r++) {
      size_t idx = ((size_t)(b * SS + qrow0 + r)) * (size_t)DM + h * DH + mb * 16 + cbase;
      ao[idx] = f2bf(o[mb][r] * rinv[r]);
    }
}

extern "C" void kernel_launch(void* const* d_in, const int* in_sizes, int n_in,
                              void* d_out, int out_size, void* d_ws, size_t ws_size,
                              hipStream_t stream) {
  (void)in_sizes; (void)n_in; (void)out_size; (void)ws_size;
  const float* x     = (const float*)d_in[0];
  const float* w_in  = (const float*)d_in[1];
  const float* w_out = (const float*)d_in[2];
  float* out = (float*)d_out;

  char* ws = (char*)d_ws;
  unsigned short* Xb  = (unsigned short*)(ws);                     // 16 MB  [4096][2048]
  unsigned short* Wit = (unsigned short*)(ws + (16ull << 20));     // 24 MB  [6144][2048]
  unsigned short* Wot = (unsigned short*)(ws + (40ull << 20));     //  8 MB  [2048][2048]
  unsigned short* Qg  = (unsigned short*)(ws + (48ull << 20));     // 16 MB  [b][h][s][d]
  unsigned short* Kg  = (unsigned short*)(ws + (64ull << 20));     // 16 MB  [b][h][s][d]
  unsigned short* Vg  = (unsigned short*)(ws + (80ull << 20));     // 16 MB  [b][h][d][s]
  unsigned short* AO  = (unsigned short*)(ws + (96ull << 20));     // 16 MB  [4096][2048]

  // x -> bf16
  f32_to_bf16_k<<<MTOT * DM / 4 / 256, 256, 0, stream>>>(x, Xb, MTOT * DM / 4);
  // w_in [2048][6144] -> Wit [6144][2048] bf16
  transpose_f32_bf16_k<<<dim3(NQKV / 32, DM / 32), 256, 0, stream>>>(w_in, Wit, DM, NQKV);
  // w_out [2048][2048] -> Wot transposed bf16
  transpose_f32_bf16_k<<<dim3(DM / 32, DM / 32), 256, 0, stream>>>(w_out, Wot, DM, DM);
  // QKV projection with split epilogue -> Qg, Kg, Vg(transposed)
  gemm_bt_k<1><<<dim3(NQKV / 128, MTOT / 128), 256, 0, stream>>>(Xb, Wit, Qg, Kg, Vg, DM, 0);
  // attention -> AO
  attn_fwd_k<<<1024, 256, 0, stream>>>(Qg, Kg, Vg, AO);
  // out = AO @ Wot^T (f32)
  gemm_bt_k<0><<<dim3(DM / 128, MTOT / 128), 256, 0, stream>>>(AO, Wot, out, nullptr, nullptr, DM, DM);
}